// Round 4
// baseline (879.793 us; speedup 1.0000x reference)
//
#include <hip/hip_runtime.h>
#include <stdint.h>

#define NEGV -1e30f
static constexpr int BATCH = 64;
static constexpr int NN = 512;
static constexpr int MM = 512;
static constexpr int NM = NN * MM;
static constexpr size_t TOTAL = (size_t)BATCH * NM;
static constexpr int ROTC = 11;   // per-batch skew-row rotation (kept, neutral)
static constexpr int PDEPTH = 16; // LDS ring depth in rows (32 KB)

// physical row of logical skew-row k for batch b (bijective per batch).
// Works for negative k: two's-complement & gives [0,511].
__device__ __forceinline__ int prow(int b, int k) {
    return (k + ROTC * b) & 511;
}

// lane n <- lane n-1 (whole-wave shift right by 1), 1 VALU op, no LDS.
__device__ __forceinline__ float wave_shr1(float x) {
    int y = __builtin_amdgcn_mov_dpp(__float_as_int(x), 0x138, 0xf, 0xf, true);
    return __int_as_float(y);
}

// counted vmcnt wait: OUR pipeline discipline, not the compiler's.
#define VMWAIT(n) asm volatile("s_waitcnt vmcnt(" #n ")" ::: "memory")

// address-space typedefs for global_load_lds
typedef __attribute__((address_space(1))) const uint32_t ga_u32;
typedef __attribute__((address_space(3))) uint32_t lds_u32;

// compile-time float4 component select (folds after macro expansion)
#define F4C(v, c) ((c) == 0 ? (v).x : (c) == 1 ? (v).y : (c) == 2 ? (v).z : (v).w)

// XOR-swizzled LDS address for 64-float rows (transpose kernels only)
__device__ __forceinline__ int swz(int row, int c) {
    return row * 64 + ((((c >> 2) ^ (row & 15)) << 2) | (c & 3));
}

// ---------------------------------------------------------------------------
// block-level max reduction (256 threads)
// ---------------------------------------------------------------------------
__device__ inline float blockMax256(float v) {
    __shared__ float sm[256];
    sm[threadIdx.x] = v;
    __syncthreads();
    for (int s = 128; s > 0; s >>= 1) {
        if ((int)threadIdx.x < s)
            sm[threadIdx.x] = fmaxf(sm[threadIdx.x], sm[threadIdx.x + s]);
        __syncthreads();
    }
    return sm[0];
}

// ===========================================================================
// Skew-transposed layout. S[prow(b,k')][r] = A[r][(k'-r)&511].
// ===========================================================================

// K0: S_D[b][prow(r+c)][r] = D[b][r][c]. Tiled via LDS (coalesced both sides).
__global__ __launch_bounds__(256) void skew_kernel(const float* __restrict__ D,
                                                   float* __restrict__ Sd) {
    __shared__ float lds[64 * 64];
    const int bi = blockIdx.x;
    const int b = bi >> 6;
    const int t = bi & 63;
    const int r0 = (t >> 3) * 64;
    const int c0 = (t & 7) * 64;
    const float* Db = D + (size_t)b * NM;
    float* So = Sd + (size_t)b * NM;
    {
        const int xg = (threadIdx.x & 15) * 4;
        const int y0 = threadIdx.x >> 4;
        for (int sw = 0; sw < 4; ++sw) {
            const int y = y0 + 16 * sw;
            const float4 v = *(const float4*)(Db + (size_t)(r0 + y) * MM + c0 + xg);
            *(float4*)(lds + swz(y, xg)) = v;
        }
    }
    __syncthreads();
    const int rp = (int)threadIdx.x & 63;
    const int s0 = (int)threadIdx.x >> 6;
    for (int it = 0; it < 32; ++it) {
        const int s = s0 + 4 * it;
        if (s >= 127) break;
        const int dcol = s - rp;
        if (dcol >= 0 && dcol < 64) {
            So[(size_t)prow(b, r0 + c0 + s) * MM + r0 + rp] = lds[swz(rp, dcol)];
        }
    }
}

// ---------------------------------------------------------------------------
// K1: wavefront DP in skew space, LDS-ring pipelined.
// One 64-lane wave per (batch, direction); lane t owns rows [8t, 8t+8).
// D rows stream via global_load_lds into a 16-slot LDS ring (fire-and-forget,
// no VGPR dest -> compiler cannot serialize on a register dependence).
// Consumption gated by counted VMWAIT(26): 13 steps x 2 gloads always sit
// between the wait and the gload it guards, independent of the (divergent,
// variable-count) guarded stores -> uniform and safe for every step incl.
// prologue. ds_read issued 2 steps ahead into a 4-pair register ring
// (compiler-managed lgkmcnt, ~2-step slack >> LDS latency).
// ---------------------------------------------------------------------------
#define LSE3(dg, up, lf, dd, out) do { \
    const float m_ = fmaxf(fmaxf((dg), (up)), (lf)); \
    const float mn_ = fminf(fminf((dg), (up)), (lf)); \
    const float md_ = __builtin_amdgcn_fmed3f((dg), (up), (lf)); \
    const float s_ = 1.f + __expf(mn_ - m_) + __expf(md_ - m_); \
    (out) = (dd) + m_ + __logf(s_); \
} while (0)

// d-component per local row c, static per DIR (bwd reads are col-reversed).
#define DC0(A, B) (DIR ? (B).w : (A).x)
#define DC1(A, B) (DIR ? (B).z : (A).y)
#define DC2(A, B) (DIR ? (B).y : (A).z)
#define DC3(A, B) (DIR ? (B).x : (A).w)
#define DC4(A, B) (DIR ? (A).w : (B).x)
#define DC5(A, B) (DIR ? (A).z : (B).y)
#define DC6(A, B) (DIR ? (A).y : (B).z)
#define DC7(A, B) (DIR ? (A).x : (B).w)

template <int DIR>
__device__ __forceinline__ void dp_skew_run(const float* __restrict__ Sdp,
                                            float* __restrict__ Sout,
                                            const int b, const int lane,
                                            float* __restrict__ ring) {
    const int t8 = lane * 8;
    const bool l0 = (lane == 0);

    float pA0 = NEGV, pA1 = NEGV, pA2 = NEGV, pA3 = NEGV,
          pA4 = NEGV, pA5 = NEGV, pA6 = NEGV, pA7 = NEGV;
    float pB0 = NEGV, pB1 = NEGV, pB2 = NEGV, pB3 = NEGV,
          pB4 = NEGV, pB5 = NEGV, pB6 = NEGV, pB7 = NEGV;
    float4 ra0, rb0, ra1, rb1, ra2, rb2, ra3, rb3;

// async-stage logical row kk into LDS slot (kk & 15): 2 x 1KB DMA, linear.
#define GLOAD(kk) do { \
        const int lr_ = DIR ? (510 - (kk)) : (kk); \
        const float* gp_ = Sdp + (size_t)prow(b, lr_) * MM + lane * 4; \
        float* lp_ = ring + (((kk) & 15) << 9); \
        __builtin_amdgcn_global_load_lds((ga_u32*)gp_, (lds_u32*)lp_, 16, 0, 0); \
        __builtin_amdgcn_global_load_lds((ga_u32*)(gp_ + 256), \
                                         (lds_u32*)(lp_ + 256), 16, 0, 0); \
    } while (0)

// register-load row kk from its LDS slot (row stored linearly; bwd reverses
// via offsets + DC component maps, same as the old direct-load scheme).
#define DSREAD(kk, A, B) do { \
        const float* sp_ = ring + (((kk) & 15) << 9); \
        if (DIR) { A = *(const float4*)(sp_ + 504 - t8); \
                   B = *(const float4*)(sp_ + 508 - t8); } \
        else     { A = *(const float4*)(sp_ + t8); \
                   B = *(const float4*)(sp_ + t8 + 4); } \
    } while (0)

#define STEP(PH, PA, PB, RA, RB, NA, NB) do { \
        const int k = kb + (PH); \
        const float ups_ = wave_shr1(PA##7); \
        const float dgs_ = wave_shr1(PB##7); \
        const float up0_ = l0 ? NEGV : ups_; \
        const float dg0_ = l0 ? ((k == 0) ? 0.f : NEGV) : dgs_; \
        const float g1_ = PB##0, g2_ = PB##1, g3_ = PB##2, g4_ = PB##3, \
                    g5_ = PB##4, g6_ = PB##5, g7_ = PB##6; \
        LSE3(dg0_, up0_, PA##0, DC0(RA, RB), PB##0); \
        LSE3(g1_, PA##0, PA##1, DC1(RA, RB), PB##1); \
        LSE3(g2_, PA##1, PA##2, DC2(RA, RB), PB##2); \
        LSE3(g3_, PA##2, PA##3, DC3(RA, RB), PB##3); \
        LSE3(g4_, PA##3, PA##4, DC4(RA, RB), PB##4); \
        LSE3(g5_, PA##4, PA##5, DC5(RA, RB), PB##5); \
        LSE3(g6_, PA##5, PA##6, DC6(RA, RB), PB##6); \
        LSE3(g7_, PA##6, PA##7, DC7(RA, RB), PB##7); \
        { \
            const int kt_ = k - t8; \
            float* sp_ = Sout + (size_t)prow(b, k) * MM + t8; \
            if (kt_ >= 3 && kt_ <= 511) { \
                *(float4*)sp_ = make_float4(PB##0, PB##1, PB##2, PB##3); \
            } else if (kt_ >= 0 && kt_ <= 514) { \
                if (kt_ <= 511)             sp_[0] = PB##0; \
                if (kt_ >= 1 && kt_ <= 512) sp_[1] = PB##1; \
                if (kt_ >= 2 && kt_ <= 513) sp_[2] = PB##2; \
                if (kt_ >= 3)               sp_[3] = PB##3; \
            } \
            if (kt_ >= 7 && kt_ <= 515) { \
                *(float4*)(sp_ + 4) = make_float4(PB##4, PB##5, PB##6, PB##7); \
            } else if (kt_ >= 4 && kt_ <= 518) { \
                if (kt_ <= 515)             sp_[4] = PB##4; \
                if (kt_ >= 5 && kt_ <= 516) sp_[5] = PB##5; \
                if (kt_ >= 6 && kt_ <= 517) sp_[6] = PB##6; \
                if (kt_ >= 7)               sp_[7] = PB##7; \
            } \
        } \
        VMWAIT(26);          /* row k+2 resident in LDS (store-independent) */ \
        DSREAD(k + 2, NA, NB); \
        GLOAD(k + 16);       /* fire-and-forget prefetch, slot (k & 15) */ \
    } while (0)

    // prologue: fill the full 16-row ring (32 vmcnt ops -> uniform counting)
    GLOAD(0);  GLOAD(1);  GLOAD(2);  GLOAD(3);
    GLOAD(4);  GLOAD(5);  GLOAD(6);  GLOAD(7);
    GLOAD(8);  GLOAD(9);  GLOAD(10); GLOAD(11);
    GLOAD(12); GLOAD(13); GLOAD(14); GLOAD(15);
    VMWAIT(28);                 // rows 0,1 landed (32 - 4 = 28)
    DSREAD(0, ra0, rb0);
    DSREAD(1, ra1, rb1);

    for (int kb = 0; kb < NN + MM; kb += 4) {
        STEP(0, pA, pB, ra0, rb0, ra2, rb2);
        STEP(1, pB, pA, ra1, rb1, ra3, rb3);
        STEP(2, pA, pB, ra2, rb2, ra0, rb0);
        STEP(3, pB, pA, ra3, rb3, ra1, rb1);
    }

#undef STEP
#undef DSREAD
#undef GLOAD
}

__global__ __launch_bounds__(64, 1) void dp_skew_kernel(const float* __restrict__ Sd,
                                                        float* __restrict__ Sf,
                                                        float* __restrict__ Sb) {
    __shared__ float ring[PDEPTH * 512];   // 32 KB D-row ring
    const int blk = blockIdx.x;
    const int b = blk & (BATCH - 1);
    const int dir = blk >> 6;
    const int lane = (int)threadIdx.x;
    const float* Sdb = Sd + (size_t)b * NM;
    if (dir) dp_skew_run<1>(Sdb, Sb + (size_t)b * NM, b, lane, ring);
    else     dp_skew_run<0>(Sdb, Sf + (size_t)b * NM, b, lane, ring);
}

// K2': logit in skew space (logical rows; all arrays share the prow mapping).
__global__ __launch_bounds__(256) void logit_skew_kernel(float* __restrict__ Sd,
                                                         const float* __restrict__ Sf,
                                                         const float* __restrict__ Sb,
                                                         float* __restrict__ partial) {
    const size_t n4 = TOTAL / 4;
    float mx = NEGV;
    const size_t stride = (size_t)gridDim.x * blockDim.x;
    for (size_t e = (size_t)blockIdx.x * blockDim.x + threadIdx.x; e < n4; e += stride) {
        const int b = (int)(e >> 16);           // NM/4 = 65536
        const int rem = (int)(e & 65535);
        const int kp = rem >> 7;                // logical skew row
        const int r4 = (rem & 127) << 2;        // col group
        const size_t base = (size_t)b * NM;
        const size_t idx = base + (size_t)prow(b, kp) * MM + r4;
        const float4 f = *(const float4*)(Sf + idx);
        const float4 d = *(const float4*)(Sd + idx);
        const int k2 = (510 - kp) & 511;
        const float4 bb = *(const float4*)(Sb + base + (size_t)prow(b, k2) * MM + (508 - r4));
        float4 v;
        v.x = f.x + bb.w - d.x;
        v.y = f.y + bb.z - d.y;
        v.z = f.z + bb.y - d.z;
        v.w = f.w + bb.x - d.w;
        *(float4*)(Sd + idx) = v;
        mx = fmaxf(mx, fmaxf(fmaxf(v.x, v.y), fmaxf(v.z, v.w)));
    }
    float bm = blockMax256(mx);
    if (threadIdx.x == 0) partial[blockIdx.x] = bm;
}

// K3: reduce partials to one scalar
__global__ __launch_bounds__(256) void finalmax_kernel(const float* __restrict__ partial,
                                                       int n,
                                                       float* __restrict__ outmax) {
    float mx = NEGV;
    for (int i = threadIdx.x; i < n; i += 256) mx = fmaxf(mx, partial[i]);
    float bm = blockMax256(mx);
    if (threadIdx.x == 0) *outmax = bm;
}

// K4': unskew + subtract max. out[i][j] = OS[(i+j) logical][i] - mx. Tiled LDS.
__global__ __launch_bounds__(256) void unskew_kernel(const float* __restrict__ OS,
                                                     float* __restrict__ out,
                                                     const float* __restrict__ maxp) {
    __shared__ float lds[127 * 64];
    const float mx = *maxp;
    const int bi = blockIdx.x;
    const int b = bi >> 6;
    const int t = bi & 63;
    const int i0 = (t >> 3) * 64;
    const int j0 = (t & 7) * 64;
    const float* Ob = OS + (size_t)b * NM;
    float* ob = out + (size_t)b * NM;
    const int base = i0 + j0;
    {
        const int xg = ((int)threadIdx.x & 15) * 4;
        const int s0 = (int)threadIdx.x >> 4;
        for (int sw = 0; sw < 8; ++sw) {
            const int s = s0 + 16 * sw;
            if (s < 127) {
                const float4 v = *(const float4*)(Ob + (size_t)prow(b, base + s) * MM + i0 + xg);
                *(float4*)(lds + swz(s, xg)) = v;
            }
        }
    }
    __syncthreads();
    const int x4 = ((int)threadIdx.x & 15) * 4;   // j - j0 group
    const int y0 = (int)threadIdx.x >> 4;         // i - i0
    for (int sw = 0; sw < 4; ++sw) {
        const int y = y0 + 16 * sw;
        float4 v;
        v.x = lds[swz(x4 + 0 + y, y)] - mx;
        v.y = lds[swz(x4 + 1 + y, y)] - mx;
        v.z = lds[swz(x4 + 2 + y, y)] - mx;
        v.w = lds[swz(x4 + 3 + y, y)] - mx;
        *(float4*)(ob + (size_t)(i0 + y) * MM + j0 + x4) = v;
    }
}

// ===========================================================================
// LEGACY PATH (round-0, known-good): used only if ws_size < 128MB + slack.
// ===========================================================================
template <int DIR>
__device__ __forceinline__ void dp_run_legacy(const float* __restrict__ Db,
                                              float* __restrict__ Rp, int lane) {
    const int i0 = lane * 8;
    const bool l0 = (lane == 0);
    const float dgb0 = l0 ? 0.f : NEGV;

#define PTRS(r) \
    const float* ldp_##r = DIR ? (Db + (size_t)(NM - 1) - (size_t)(i0 + r) * MM) \
                               : (Db + (size_t)(i0 + r) * MM); \
    float* stp_##r = DIR ? (Rp + (size_t)(NM - 1) - (size_t)(i0 + r) * MM) \
                         : (Rp + (size_t)(i0 + r) * MM);
    PTRS(0) PTRS(1) PTRS(2) PTRS(3) PTRS(4) PTRS(5) PTRS(6) PTRS(7)

#define LOADG(r, dst, jgexpr) do { \
        int jc_ = (jgexpr); \
        jc_ = jc_ < 0 ? 0 : jc_; jc_ = jc_ > (MM - 4) ? (MM - 4) : jc_; \
        if (DIR) { const float4 t_ = *(const float4*)(ldp_##r - jc_ - 3); \
                   dst = make_float4(t_.w, t_.z, t_.y, t_.x); } \
        else     { dst = *(const float4*)(ldp_##r + jc_); } \
    } while (0)

#define INIT(r) \
    float p1_##r = NEGV, p2_##r = NEGV, p3_##r = NEGV, np_##r = NEGV; \
    float4 dc_##r, dn_##r; \
    LOADG(r, dn_##r, 0); dc_##r = dn_##r;
    INIT(0) INIT(1) INIT(2) INIT(3) INIT(4) INIT(5) INIT(6) INIT(7)

#define SWAPLOAD(r) do { dc_##r = dn_##r; LOADG(r, dn_##r, jj - (r) + 4); } while (0)

#define CELL(r, KK, DGIN, UPIN, DGB) do { \
        const int j_ = jj - (r); \
        const bool jz_ = (j_ == 0); \
        const float dg_ = jz_ ? (DGB) : (DGIN); \
        const float up_ = (UPIN); \
        const float lf_ = jz_ ? NEGV : p1_##r; \
        const float m_  = fmaxf(fmaxf(dg_, up_), lf_); \
        const float mn_ = fminf(fminf(dg_, up_), lf_); \
        const float md_ = __builtin_amdgcn_fmed3f(dg_, up_, lf_); \
        const float s_  = 1.f + __expf(mn_ - m_) + __expf(md_ - m_); \
        np_##r = F4C(dc_##r, ((KK) - (r)) & 3) + m_ + __logf(s_); \
    } while (0)

#define STORE(r) do { \
        const int j_ = jj - (r); \
        if (j_ >= 3 && j_ < MM) { \
            if (DIR) *(float4*)(stp_##r - j_) = \
                make_float4(np_##r, p1_##r, p2_##r, p3_##r); \
            else     *(float4*)(stp_##r + j_ - 3) = \
                make_float4(p3_##r, p2_##r, p1_##r, np_##r); \
        } \
    } while (0)

#define SHIFT(r) do { p3_##r = p2_##r; p2_##r = p1_##r; p1_##r = np_##r; } while (0)

#define LSTEP(KK, LA, LB, SA, SB) do { \
        const int jj = kbj + (KK); \
        SWAPLOAD(LA); SWAPLOAD(LB); \
        const float ups_ = wave_shr1(p1_7); \
        const float dgs_ = wave_shr1(p2_7); \
        const float up0r = l0 ? NEGV : ups_; \
        const float dg0r = l0 ? NEGV : dgs_; \
        CELL(0, KK, dg0r, up0r, dgb0); \
        CELL(1, KK, p2_0, p1_0, NEGV); \
        CELL(2, KK, p2_1, p1_1, NEGV); \
        CELL(3, KK, p2_2, p1_2, NEGV); \
        CELL(4, KK, p2_3, p1_3, NEGV); \
        CELL(5, KK, p2_4, p1_4, NEGV); \
        CELL(6, KK, p2_5, p1_5, NEGV); \
        CELL(7, KK, p2_6, p1_6, NEGV); \
        STORE(SA); STORE(SB); \
        SHIFT(0); SHIFT(1); SHIFT(2); SHIFT(3); \
        SHIFT(4); SHIFT(5); SHIFT(6); SHIFT(7); \
    } while (0)

    for (int kb = 0; kb < NN + MM; kb += 4) {
        const int kbj = kb - i0;
        LSTEP(0, 0, 4, 1, 5);
        LSTEP(1, 1, 5, 2, 6);
        LSTEP(2, 2, 6, 3, 7);
        LSTEP(3, 3, 7, 0, 4);
    }

#undef PTRS
#undef LOADG
#undef INIT
#undef SWAPLOAD
#undef CELL
#undef STORE
#undef SHIFT
#undef LSTEP
}

__global__ __launch_bounds__(64, 1) void dp_kernel_legacy(const float* __restrict__ D,
                                                          float* __restrict__ Rf,
                                                          float* __restrict__ Rb) {
    const int blk = blockIdx.x;
    const int b = blk & (BATCH - 1);
    const int dir = blk >> 6;
    const float* __restrict__ Db = D + (size_t)b * NM;
    const int lane = (int)threadIdx.x;
    if (dir) dp_run_legacy<1>(Db, Rb + (size_t)b * NM, lane);
    else     dp_run_legacy<0>(Db, Rf + (size_t)b * NM, lane);
}

__global__ __launch_bounds__(256) void logit_kernel(const float4* __restrict__ D,
                                                    const float4* __restrict__ Rb,
                                                    float4* __restrict__ out,
                                                    float* __restrict__ partial) {
    const size_t n4 = TOTAL / 4;
    float mx = NEGV;
    const size_t stride = (size_t)gridDim.x * blockDim.x;
    for (size_t idx = (size_t)blockIdx.x * blockDim.x + threadIdx.x; idx < n4;
         idx += stride) {
        float4 f = out[idx], bb = Rb[idx], d = D[idx];
        float4 v = make_float4(f.x + bb.x - d.x, f.y + bb.y - d.y,
                               f.z + bb.z - d.z, f.w + bb.w - d.w);
        out[idx] = v;
        mx = fmaxf(mx, fmaxf(fmaxf(v.x, v.y), fmaxf(v.z, v.w)));
    }
    float bm = blockMax256(mx);
    if (threadIdx.x == 0) partial[blockIdx.x] = bm;
}

__global__ __launch_bounds__(256) void sub_kernel(float4* __restrict__ out,
                                                  const float* __restrict__ maxp) {
    const float mx = *maxp;
    const size_t n4 = TOTAL / 4;
    const size_t stride = (size_t)gridDim.x * blockDim.x;
    for (size_t idx = (size_t)blockIdx.x * blockDim.x + threadIdx.x; idx < n4;
         idx += stride) {
        float4 v = out[idx];
        v.x -= mx; v.y -= mx; v.z -= mx; v.w -= mx;
        out[idx] = v;
    }
}

extern "C" void kernel_launch(void* const* d_in, const int* in_sizes, int n_in,
                              void* d_out, int out_size, void* d_ws, size_t ws_size,
                              hipStream_t stream) {
    const float* D = (const float*)d_in[0];
    float* out = (float*)d_out;

    const size_t needed = (2 * TOTAL + 4096) * sizeof(float);
    if (ws_size >= needed) {
        float* Sd = (float*)d_ws;
        float* Sb = Sd + TOTAL;
        float* partial = Sd + 2 * TOTAL;
        float* maxp = partial + 2048;

        skew_kernel<<<4096, 256, 0, stream>>>(D, Sd);
        dp_skew_kernel<<<128, 64, 0, stream>>>(Sd, out, Sb);
        logit_skew_kernel<<<2048, 256, 0, stream>>>(Sd, out, Sb, partial);
        finalmax_kernel<<<1, 256, 0, stream>>>(partial, 2048, maxp);
        unskew_kernel<<<4096, 256, 0, stream>>>(Sd, out, maxp);
    } else {
        float* Rb = (float*)d_ws;
        float* partial = Rb + TOTAL;
        float* maxp = partial + 2048;

        dp_kernel_legacy<<<128, 64, 0, stream>>>(D, out, Rb);
        logit_kernel<<<2048, 256, 0, stream>>>((const float4*)D, (const float4*)Rb,
                                               (float4*)out, partial);
        finalmax_kernel<<<1, 256, 0, stream>>>(partial, 2048, maxp);
        sub_kernel<<<2048, 256, 0, stream>>>((float4*)out, maxp);
    }
}

// Round 5
// 860.204 us; speedup vs baseline: 1.0228x; 1.0228x over previous
//
#include <hip/hip_runtime.h>
#include <stdint.h>

#define NEGV -1e30f
static constexpr int BATCH = 64;
static constexpr int NN = 512;
static constexpr int MM = 512;
static constexpr int NM = NN * MM;
static constexpr size_t TOTAL = (size_t)BATCH * NM;
static constexpr int ROTC = 11;   // per-batch skew-row rotation (kept, neutral)

typedef float f32x4 __attribute__((ext_vector_type(4)));

// physical row of logical skew-row k for batch b (bijective per batch).
// Works for negative k: two's-complement & gives [0,511].
__device__ __forceinline__ int prow(int b, int k) {
    return (k + ROTC * b) & 511;
}

// lane n <- lane n-1 (whole-wave shift right by 1), 1 VALU op, no LDS.
__device__ __forceinline__ float wave_shr1(float x) {
    int y = __builtin_amdgcn_mov_dpp(__float_as_int(x), 0x138, 0xf, 0xf, true);
    return __int_as_float(y);
}

// compile-time float4 component select (folds after macro expansion)
#define F4C(v, c) ((c) == 0 ? (v).x : (c) == 1 ? (v).y : (c) == 2 ? (v).z : (v).w)

// XOR-swizzled LDS address for 64-float rows (transpose kernels only)
__device__ __forceinline__ int swz(int row, int c) {
    return row * 64 + ((((c >> 2) ^ (row & 15)) << 2) | (c & 3));
}

// ---------------------------------------------------------------------------
// block-level max reduction (256 threads)
// ---------------------------------------------------------------------------
__device__ inline float blockMax256(float v) {
    __shared__ float sm[256];
    sm[threadIdx.x] = v;
    __syncthreads();
    for (int s = 128; s > 0; s >>= 1) {
        if ((int)threadIdx.x < s)
            sm[threadIdx.x] = fmaxf(sm[threadIdx.x], sm[threadIdx.x + s]);
        __syncthreads();
    }
    return sm[0];
}

// ===========================================================================
// Skew-transposed layout. S[prow(b,k')][r] = A[r][(k'-r)&511].
// ===========================================================================

// K0: S_D[b][prow(r+c)][r] = D[b][r][c]. Tiled via LDS (coalesced both sides).
__global__ __launch_bounds__(256) void skew_kernel(const float* __restrict__ D,
                                                   float* __restrict__ Sd) {
    __shared__ float lds[64 * 64];
    const int bi = blockIdx.x;
    const int b = bi >> 6;
    const int t = bi & 63;
    const int r0 = (t >> 3) * 64;
    const int c0 = (t & 7) * 64;
    const float* Db = D + (size_t)b * NM;
    float* So = Sd + (size_t)b * NM;
    {
        const int xg = (threadIdx.x & 15) * 4;
        const int y0 = threadIdx.x >> 4;
        for (int sw = 0; sw < 4; ++sw) {
            const int y = y0 + 16 * sw;
            const float4 v = *(const float4*)(Db + (size_t)(r0 + y) * MM + c0 + xg);
            *(float4*)(lds + swz(y, xg)) = v;
        }
    }
    __syncthreads();
    const int rp = (int)threadIdx.x & 63;
    const int s0 = (int)threadIdx.x >> 6;
    for (int it = 0; it < 32; ++it) {
        const int s = s0 + 4 * it;
        if (s >= 127) break;
        const int dcol = s - rp;
        if (dcol >= 0 && dcol < 64) {
            So[(size_t)prow(b, r0 + c0 + s) * MM + r0 + rp] = lds[swz(rp, dcol)];
        }
    }
}

// ---------------------------------------------------------------------------
// K1: wavefront DP in skew space, register-ring pipelined with INLINE-ASM
// loads. One 64-lane wave per (batch, direction); lane t owns rows [8t,8t+8).
// D rows load straight to VGPRs via asm global_load_dwordx4 (invisible to the
// compiler's waitcnt accounting -> it cannot insert serializing waits), 8-deep
// named register ring, 8-phase unrolled loop. Consumption gated by OUR counted
// s_waitcnt vmcnt(14) + sched_barrier(0) (rule #18 fence). Safety: row k's 2
// loads issue at step k-8; minimum newer vm-ops at step k's gate = 7 steps x 2
// loads = 14, independent of the (divergent, variable-count) stores -> the
// gate always drains row k, while typically keeping ~14-16 ops (~4 steps) in
// flight. Numerics/guards/stores identical to the verified round-2 kernel.
// ---------------------------------------------------------------------------
#define LSE3(dg, up, lf, dd, out) do { \
    const float m_ = fmaxf(fmaxf((dg), (up)), (lf)); \
    const float mn_ = fminf(fminf((dg), (up)), (lf)); \
    const float md_ = __builtin_amdgcn_fmed3f((dg), (up), (lf)); \
    const float s_ = 1.f + __expf(mn_ - m_) + __expf(md_ - m_); \
    (out) = (dd) + m_ + __logf(s_); \
} while (0)

// d-component per local row c, static per DIR (bwd reads are col-reversed).
#define DC0(A, B) (DIR ? (B)[3] : (A)[0])
#define DC1(A, B) (DIR ? (B)[2] : (A)[1])
#define DC2(A, B) (DIR ? (B)[1] : (A)[2])
#define DC3(A, B) (DIR ? (B)[0] : (A)[3])
#define DC4(A, B) (DIR ? (A)[3] : (B)[0])
#define DC5(A, B) (DIR ? (A)[2] : (B)[1])
#define DC6(A, B) (DIR ? (A)[1] : (B)[2])
#define DC7(A, B) (DIR ? (A)[0] : (B)[3])

template <int DIR>
__device__ __forceinline__ void dp_skew_run(const float* __restrict__ Sdp,
                                            float* __restrict__ Sout,
                                            const int b, const int lane) {
    const int t8 = lane * 8;
    const bool l0 = (lane == 0);

    float pA0 = NEGV, pA1 = NEGV, pA2 = NEGV, pA3 = NEGV,
          pA4 = NEGV, pA5 = NEGV, pA6 = NEGV, pA7 = NEGV;
    float pB0 = NEGV, pB1 = NEGV, pB2 = NEGV, pB3 = NEGV,
          pB4 = NEGV, pB5 = NEGV, pB6 = NEGV, pB7 = NEGV;
    f32x4 r0a, r0b, r1a, r1b, r2a, r2b, r3a, r3b,
          r4a, r4b, r5a, r5b, r6a, r6b, r7a, r7b;

// fire-and-forget asm loads of logical row kk into register pair (A,B).
#define RLOADA(kk, A, B) do { \
        const int lr_ = DIR ? (510 - (kk)) : (kk); \
        const float* rp_ = Sdp + (size_t)prow(b, lr_) * MM; \
        const float* pa_ = DIR ? (rp_ + 504 - t8) : (rp_ + t8); \
        const float* pb_ = DIR ? (rp_ + 508 - t8) : (rp_ + t8 + 4); \
        asm volatile("global_load_dwordx4 %0, %1, off" : "=v"(A) : "v"(pa_)); \
        asm volatile("global_load_dwordx4 %0, %1, off" : "=v"(B) : "v"(pb_)); \
    } while (0)

// counted gate: row k's loads (issued 8 steps ago) are guaranteed complete;
// sched_barrier keeps the register-only cell ops from hoisting above it.
#define GATE() do { \
        asm volatile("s_waitcnt vmcnt(14)" ::: "memory"); \
        __builtin_amdgcn_sched_barrier(0); \
    } while (0)

#define STEP(PH, PA, PB, RA, RB) do { \
        const int k = kb + (PH); \
        GATE(); \
        const float ups_ = wave_shr1(PA##7); \
        const float dgs_ = wave_shr1(PB##7); \
        const float up0_ = l0 ? NEGV : ups_; \
        const float dg0_ = l0 ? ((k == 0) ? 0.f : NEGV) : dgs_; \
        const float g1_ = PB##0, g2_ = PB##1, g3_ = PB##2, g4_ = PB##3, \
                    g5_ = PB##4, g6_ = PB##5, g7_ = PB##6; \
        LSE3(dg0_, up0_, PA##0, DC0(RA, RB), PB##0); \
        LSE3(g1_, PA##0, PA##1, DC1(RA, RB), PB##1); \
        LSE3(g2_, PA##1, PA##2, DC2(RA, RB), PB##2); \
        LSE3(g3_, PA##2, PA##3, DC3(RA, RB), PB##3); \
        LSE3(g4_, PA##3, PA##4, DC4(RA, RB), PB##4); \
        LSE3(g5_, PA##4, PA##5, DC5(RA, RB), PB##5); \
        LSE3(g6_, PA##5, PA##6, DC6(RA, RB), PB##6); \
        LSE3(g7_, PA##6, PA##7, DC7(RA, RB), PB##7); \
        { \
            const int kt_ = k - t8; \
            float* sp_ = Sout + (size_t)prow(b, k) * MM + t8; \
            if (kt_ >= 3 && kt_ <= 511) { \
                *(float4*)sp_ = make_float4(PB##0, PB##1, PB##2, PB##3); \
            } else if (kt_ >= 0 && kt_ <= 514) { \
                if (kt_ <= 511)             sp_[0] = PB##0; \
                if (kt_ >= 1 && kt_ <= 512) sp_[1] = PB##1; \
                if (kt_ >= 2 && kt_ <= 513) sp_[2] = PB##2; \
                if (kt_ >= 3)               sp_[3] = PB##3; \
            } \
            if (kt_ >= 7 && kt_ <= 515) { \
                *(float4*)(sp_ + 4) = make_float4(PB##4, PB##5, PB##6, PB##7); \
            } else if (kt_ >= 4 && kt_ <= 518) { \
                if (kt_ <= 515)             sp_[4] = PB##4; \
                if (kt_ >= 5 && kt_ <= 516) sp_[5] = PB##5; \
                if (kt_ >= 6 && kt_ <= 517) sp_[6] = PB##6; \
                if (kt_ >= 7)               sp_[7] = PB##7; \
            } \
        } \
        RLOADA(k + 8, RA, RB);   /* refill the just-consumed ring slot */ \
    } while (0)

    // prologue: fill the 8-deep register ring (16 asm loads in flight)
    RLOADA(0, r0a, r0b); RLOADA(1, r1a, r1b);
    RLOADA(2, r2a, r2b); RLOADA(3, r3a, r3b);
    RLOADA(4, r4a, r4b); RLOADA(5, r5a, r5b);
    RLOADA(6, r6a, r6b); RLOADA(7, r7a, r7b);

    for (int kb = 0; kb < NN + MM; kb += 8) {
        STEP(0, pA, pB, r0a, r0b);
        STEP(1, pB, pA, r1a, r1b);
        STEP(2, pA, pB, r2a, r2b);
        STEP(3, pB, pA, r3a, r3b);
        STEP(4, pA, pB, r4a, r4b);
        STEP(5, pB, pA, r5a, r5b);
        STEP(6, pA, pB, r6a, r6b);
        STEP(7, pB, pA, r7a, r7b);
    }

#undef STEP
#undef GATE
#undef RLOADA
}

__global__ __launch_bounds__(64, 1) void dp_skew_kernel(const float* __restrict__ Sd,
                                                        float* __restrict__ Sf,
                                                        float* __restrict__ Sb) {
    const int blk = blockIdx.x;
    const int b = blk & (BATCH - 1);
    const int dir = blk >> 6;
    const int lane = (int)threadIdx.x;
    const float* Sdb = Sd + (size_t)b * NM;
    if (dir) dp_skew_run<1>(Sdb, Sb + (size_t)b * NM, b, lane);
    else     dp_skew_run<0>(Sdb, Sf + (size_t)b * NM, b, lane);
}

// K2': logit in skew space (logical rows; all arrays share the prow mapping).
__global__ __launch_bounds__(256) void logit_skew_kernel(float* __restrict__ Sd,
                                                         const float* __restrict__ Sf,
                                                         const float* __restrict__ Sb,
                                                         float* __restrict__ partial) {
    const size_t n4 = TOTAL / 4;
    float mx = NEGV;
    const size_t stride = (size_t)gridDim.x * blockDim.x;
    for (size_t e = (size_t)blockIdx.x * blockDim.x + threadIdx.x; e < n4; e += stride) {
        const int b = (int)(e >> 16);           // NM/4 = 65536
        const int rem = (int)(e & 65535);
        const int kp = rem >> 7;                // logical skew row
        const int r4 = (rem & 127) << 2;        // col group
        const size_t base = (size_t)b * NM;
        const size_t idx = base + (size_t)prow(b, kp) * MM + r4;
        const float4 f = *(const float4*)(Sf + idx);
        const float4 d = *(const float4*)(Sd + idx);
        const int k2 = (510 - kp) & 511;
        const float4 bb = *(const float4*)(Sb + base + (size_t)prow(b, k2) * MM + (508 - r4));
        float4 v;
        v.x = f.x + bb.w - d.x;
        v.y = f.y + bb.z - d.y;
        v.z = f.z + bb.y - d.z;
        v.w = f.w + bb.x - d.w;
        *(float4*)(Sd + idx) = v;
        mx = fmaxf(mx, fmaxf(fmaxf(v.x, v.y), fmaxf(v.z, v.w)));
    }
    float bm = blockMax256(mx);
    if (threadIdx.x == 0) partial[blockIdx.x] = bm;
}

// K3: reduce partials to one scalar
__global__ __launch_bounds__(256) void finalmax_kernel(const float* __restrict__ partial,
                                                       int n,
                                                       float* __restrict__ outmax) {
    float mx = NEGV;
    for (int i = threadIdx.x; i < n; i += 256) mx = fmaxf(mx, partial[i]);
    float bm = blockMax256(mx);
    if (threadIdx.x == 0) *outmax = bm;
}

// K4': unskew + subtract max. out[i][j] = OS[(i+j) logical][i] - mx. Tiled LDS.
__global__ __launch_bounds__(256) void unskew_kernel(const float* __restrict__ OS,
                                                     float* __restrict__ out,
                                                     const float* __restrict__ maxp) {
    __shared__ float lds[127 * 64];
    const float mx = *maxp;
    const int bi = blockIdx.x;
    const int b = bi >> 6;
    const int t = bi & 63;
    const int i0 = (t >> 3) * 64;
    const int j0 = (t & 7) * 64;
    const float* Ob = OS + (size_t)b * NM;
    float* ob = out + (size_t)b * NM;
    const int base = i0 + j0;
    {
        const int xg = ((int)threadIdx.x & 15) * 4;
        const int s0 = (int)threadIdx.x >> 4;
        for (int sw = 0; sw < 8; ++sw) {
            const int s = s0 + 16 * sw;
            if (s < 127) {
                const float4 v = *(const float4*)(Ob + (size_t)prow(b, base + s) * MM + i0 + xg);
                *(float4*)(lds + swz(s, xg)) = v;
            }
        }
    }
    __syncthreads();
    const int x4 = ((int)threadIdx.x & 15) * 4;   // j - j0 group
    const int y0 = (int)threadIdx.x >> 4;         // i - i0
    for (int sw = 0; sw < 4; ++sw) {
        const int y = y0 + 16 * sw;
        float4 v;
        v.x = lds[swz(x4 + 0 + y, y)] - mx;
        v.y = lds[swz(x4 + 1 + y, y)] - mx;
        v.z = lds[swz(x4 + 2 + y, y)] - mx;
        v.w = lds[swz(x4 + 3 + y, y)] - mx;
        *(float4*)(ob + (size_t)(i0 + y) * MM + j0 + x4) = v;
    }
}

// ===========================================================================
// LEGACY PATH (round-0, known-good): used only if ws_size < 128MB + slack.
// ===========================================================================
template <int DIR>
__device__ __forceinline__ void dp_run_legacy(const float* __restrict__ Db,
                                              float* __restrict__ Rp, int lane) {
    const int i0 = lane * 8;
    const bool l0 = (lane == 0);
    const float dgb0 = l0 ? 0.f : NEGV;

#define PTRS(r) \
    const float* ldp_##r = DIR ? (Db + (size_t)(NM - 1) - (size_t)(i0 + r) * MM) \
                               : (Db + (size_t)(i0 + r) * MM); \
    float* stp_##r = DIR ? (Rp + (size_t)(NM - 1) - (size_t)(i0 + r) * MM) \
                         : (Rp + (size_t)(i0 + r) * MM);
    PTRS(0) PTRS(1) PTRS(2) PTRS(3) PTRS(4) PTRS(5) PTRS(6) PTRS(7)

#define LOADG(r, dst, jgexpr) do { \
        int jc_ = (jgexpr); \
        jc_ = jc_ < 0 ? 0 : jc_; jc_ = jc_ > (MM - 4) ? (MM - 4) : jc_; \
        if (DIR) { const float4 t_ = *(const float4*)(ldp_##r - jc_ - 3); \
                   dst = make_float4(t_.w, t_.z, t_.y, t_.x); } \
        else     { dst = *(const float4*)(ldp_##r + jc_); } \
    } while (0)

#define INIT(r) \
    float p1_##r = NEGV, p2_##r = NEGV, p3_##r = NEGV, np_##r = NEGV; \
    float4 dc_##r, dn_##r; \
    LOADG(r, dn_##r, 0); dc_##r = dn_##r;
    INIT(0) INIT(1) INIT(2) INIT(3) INIT(4) INIT(5) INIT(6) INIT(7)

#define SWAPLOAD(r) do { dc_##r = dn_##r; LOADG(r, dn_##r, jj - (r) + 4); } while (0)

#define CELL(r, KK, DGIN, UPIN, DGB) do { \
        const int j_ = jj - (r); \
        const bool jz_ = (j_ == 0); \
        const float dg_ = jz_ ? (DGB) : (DGIN); \
        const float up_ = (UPIN); \
        const float lf_ = jz_ ? NEGV : p1_##r; \
        const float m_  = fmaxf(fmaxf(dg_, up_), lf_); \
        const float mn_ = fminf(fminf(dg_, up_), lf_); \
        const float md_ = __builtin_amdgcn_fmed3f(dg_, up_, lf_); \
        const float s_  = 1.f + __expf(mn_ - m_) + __expf(md_ - m_); \
        np_##r = F4C(dc_##r, ((KK) - (r)) & 3) + m_ + __logf(s_); \
    } while (0)

#define STORE(r) do { \
        const int j_ = jj - (r); \
        if (j_ >= 3 && j_ < MM) { \
            if (DIR) *(float4*)(stp_##r - j_) = \
                make_float4(np_##r, p1_##r, p2_##r, p3_##r); \
            else     *(float4*)(stp_##r + j_ - 3) = \
                make_float4(p3_##r, p2_##r, p1_##r, np_##r); \
        } \
    } while (0)

#define SHIFT(r) do { p3_##r = p2_##r; p2_##r = p1_##r; p1_##r = np_##r; } while (0)

#define LSTEP(KK, LA, LB, SA, SB) do { \
        const int jj = kbj + (KK); \
        SWAPLOAD(LA); SWAPLOAD(LB); \
        const float ups_ = wave_shr1(p1_7); \
        const float dgs_ = wave_shr1(p2_7); \
        const float up0r = l0 ? NEGV : ups_; \
        const float dg0r = l0 ? NEGV : dgs_; \
        CELL(0, KK, dg0r, up0r, dgb0); \
        CELL(1, KK, p2_0, p1_0, NEGV); \
        CELL(2, KK, p2_1, p1_1, NEGV); \
        CELL(3, KK, p2_2, p1_2, NEGV); \
        CELL(4, KK, p2_3, p1_3, NEGV); \
        CELL(5, KK, p2_4, p1_4, NEGV); \
        CELL(6, KK, p2_5, p1_5, NEGV); \
        CELL(7, KK, p2_6, p1_6, NEGV); \
        STORE(SA); STORE(SB); \
        SHIFT(0); SHIFT(1); SHIFT(2); SHIFT(3); \
        SHIFT(4); SHIFT(5); SHIFT(6); SHIFT(7); \
    } while (0)

    for (int kb = 0; kb < NN + MM; kb += 4) {
        const int kbj = kb - i0;
        LSTEP(0, 0, 4, 1, 5);
        LSTEP(1, 1, 5, 2, 6);
        LSTEP(2, 2, 6, 3, 7);
        LSTEP(3, 3, 7, 0, 4);
    }

#undef PTRS
#undef LOADG
#undef INIT
#undef SWAPLOAD
#undef CELL
#undef STORE
#undef SHIFT
#undef LSTEP
}

__global__ __launch_bounds__(64, 1) void dp_kernel_legacy(const float* __restrict__ D,
                                                          float* __restrict__ Rf,
                                                          float* __restrict__ Rb) {
    const int blk = blockIdx.x;
    const int b = blk & (BATCH - 1);
    const int dir = blk >> 6;
    const float* __restrict__ Db = D + (size_t)b * NM;
    const int lane = (int)threadIdx.x;
    if (dir) dp_run_legacy<1>(Db, Rb + (size_t)b * NM, lane);
    else     dp_run_legacy<0>(Db, Rf + (size_t)b * NM, lane);
}

__global__ __launch_bounds__(256) void logit_kernel(const float4* __restrict__ D,
                                                    const float4* __restrict__ Rb,
                                                    float4* __restrict__ out,
                                                    float* __restrict__ partial) {
    const size_t n4 = TOTAL / 4;
    float mx = NEGV;
    const size_t stride = (size_t)gridDim.x * blockDim.x;
    for (size_t idx = (size_t)blockIdx.x * blockDim.x + threadIdx.x; idx < n4;
         idx += stride) {
        float4 f = out[idx], bb = Rb[idx], d = D[idx];
        float4 v = make_float4(f.x + bb.x - d.x, f.y + bb.y - d.y,
                               f.z + bb.z - d.z, f.w + bb.w - d.w);
        out[idx] = v;
        mx = fmaxf(mx, fmaxf(fmaxf(v.x, v.y), fmaxf(v.z, v.w)));
    }
    float bm = blockMax256(mx);
    if (threadIdx.x == 0) partial[blockIdx.x] = bm;
}

__global__ __launch_bounds__(256) void sub_kernel(float4* __restrict__ out,
                                                  const float* __restrict__ maxp) {
    const float mx = *maxp;
    const size_t n4 = TOTAL / 4;
    const size_t stride = (size_t)gridDim.x * blockDim.x;
    for (size_t idx = (size_t)blockIdx.x * blockDim.x + threadIdx.x; idx < n4;
         idx += stride) {
        float4 v = out[idx];
        v.x -= mx; v.y -= mx; v.z -= mx; v.w -= mx;
        out[idx] = v;
    }
}

extern "C" void kernel_launch(void* const* d_in, const int* in_sizes, int n_in,
                              void* d_out, int out_size, void* d_ws, size_t ws_size,
                              hipStream_t stream) {
    const float* D = (const float*)d_in[0];
    float* out = (float*)d_out;

    const size_t needed = (2 * TOTAL + 4096) * sizeof(float);
    if (ws_size >= needed) {
        float* Sd = (float*)d_ws;
        float* Sb = Sd + TOTAL;
        float* partial = Sd + 2 * TOTAL;
        float* maxp = partial + 2048;

        skew_kernel<<<4096, 256, 0, stream>>>(D, Sd);
        dp_skew_kernel<<<128, 64, 0, stream>>>(Sd, out, Sb);
        logit_skew_kernel<<<2048, 256, 0, stream>>>(Sd, out, Sb, partial);
        finalmax_kernel<<<1, 256, 0, stream>>>(partial, 2048, maxp);
        unskew_kernel<<<4096, 256, 0, stream>>>(Sd, out, maxp);
    } else {
        float* Rb = (float*)d_ws;
        float* partial = Rb + TOTAL;
        float* maxp = partial + 2048;

        dp_kernel_legacy<<<128, 64, 0, stream>>>(D, out, Rb);
        logit_kernel<<<2048, 256, 0, stream>>>((const float4*)D, (const float4*)Rb,
                                               (float4*)out, partial);
        finalmax_kernel<<<1, 256, 0, stream>>>(partial, 2048, maxp);
        sub_kernel<<<2048, 256, 0, stream>>>((float4*)out, maxp);
    }
}